// Round 8
// baseline (69.071 us; speedup 1.0000x reference)
//
#include <hip/hip_runtime.h>

#define K_BINS 1025
#define T_LEN  2000
#define NF     128

__device__ __forceinline__ float softplusf(float x) {
    // matches jax.nn.softplus = max(x,0) + log1p(exp(-|x|))
    return fmaxf(x, 0.0f) + log1pf(expf(-fabsf(x)));
}

// out[b2][t][4*bp + w] = sum_k w_f(k) * spec[bp][k][t],  f = b2 + 32*w
// Block = (bp-quad q, B-pair Bp, t-chunk th). 1024 thr = 16 waves (j,p).
// Wave (j,p) handles TWO filter-quads, paired for load balance:
//   task0: band j,   b2-quad Bp    (filters 4Bp+32j+i)
//   task1: band 3-j, b2-quad 7-Bp  (filters 4(7-Bp)+32(3-j)+i)
// Quad union sizes rows(h), h = 8*band+B, increase monotonically with
// frequency; pairing h with 31-h makes per-wave totals ~constant -> no
// intra-block straggler waves (R6/R7's limiter).
// Each walk is the merged-runs union of 4 adjacent filters (in-register
// mel-overlap reuse, exact gap skip) with a 2-deep load pipeline.
// Epilogue per (task, i): LDS [256][17] transpose -> full 64 B line stores.
__global__ __launch_bounds__(1024) void fb_fused(
        const float* __restrict__ spec,
        const float* __restrict__ cf,
        const float* __restrict__ bwv,
        const float* __restrict__ fs,
        float*       __restrict__ out) {
    const int q    = blockIdx.x;   // bp-quad 0..7 (id%8 -> XCD q)
    const int Bp   = blockIdx.y;   // B-pair 0..3 -> quads {Bp, 7-Bp}
    const int th   = blockIdx.z;   // t-chunk 0..7
    const int tid  = threadIdx.x;
    const int lane = tid & 63;
    const int wid  = tid >> 6;     // 0..15
    const int j    = wid >> 2;     // band 0..3
    const int p    = wid & 3;      // bp-local 0..3
    const int bp   = 4 * q + p;
    const int t0   = 256 * th;
    const int Lt   = (th < 7) ? 256 : 208;   // 2000 = 7*256 + 208
    const int Lq   = Lt >> 2;                // float4s in chunk
    const int li   = min(lane, Lq - 1);      // clamped (tail chunk only)

    const float4* base4 =
        (const float4*)(spec + (size_t)bp * (K_BINS * (size_t)T_LEN) + t0);

    float4 acc[2][4];
#pragma unroll
    for (int s = 0; s < 2; ++s)
#pragma unroll
        for (int i = 0; i < 4; ++i) acc[s][i] = make_float4(0.f, 0.f, 0.f, 0.f);

#pragma unroll
    for (int s = 0; s < 2; ++s) {
        const int band  = s ? 3 - j : j;
        const int Bq    = s ? 7 - Bp : Bp;
        const int fbase = 4 * Bq + 32 * band;

        float icl[4], irc[4], Af[4], Bf[4];
        int   klo[4], khi[4];
#pragma unroll
        for (int i = 0; i < 4; ++i) {
            const int f = fbase + i;
            float c  = cf[f];
            float bw = softplusf(bwv[f]) + 0.001f;
            float s0 = softplusf(fs[2 * f])     + 0.1f;
            float s1 = softplusf(fs[2 * f + 1]) + 0.1f;
            float left  = c - bw * s0;
            float right = c + bw * s1;
            icl[i] = 1.0f / (c - left + 1e-8f);
            irc[i] = 1.0f / (right - c + 1e-8f);
            Af[i]  = left * icl[i];            // rise = fk*icl - Af
            Bf[i]  = fmaf(c, irc[i], 1.0f);    // fall = Bf - fk*irc
            klo[i] = max(0, (int)ceilf(left));
            khi[i] = min(K_BINS - 1, (int)floorf(right));
        }

        // merge supports into <=4 contiguous runs (klo ascending in i)
        int rs[4], re[4], nr = 0;
        {
            int cs = klo[0], ce = khi[0];
#pragma unroll
            for (int i = 1; i < 4; ++i) {
                if (klo[i] <= ce + 1) ce = max(ce, khi[i]);
                else { rs[nr] = cs; re[nr] = ce; ++nr; cs = klo[i]; ce = khi[i]; }
            }
            rs[nr] = cs; re[nr] = ce; ++nr;
        }

        // branch-free union walk, 2-deep pipelined (1 float4/row/lane)
        int rcur = 0;
        int kcur = rs[0];
        float4 v = base4[(size_t)kcur * 500 + li];
        while (kcur >= 0) {
            int knext, rnext = rcur;
            if (kcur + 1 <= re[rcur])      knext = kcur + 1;
            else if (rcur + 1 < nr)        { rnext = rcur + 1; knext = rs[rnext]; }
            else                           knext = -1;

            float4 n;
            if (knext >= 0) n = base4[(size_t)knext * 500 + li];

            float fk = (float)kcur;
#pragma unroll
            for (int i = 0; i < 4; ++i) {
                float rise = fmaf(fk, icl[i], -Af[i]);
                float fall = fmaf(-fk, irc[i], Bf[i]);
                float wg   = fmaxf(0.0f, fminf(rise, fall));
                acc[s][i].x = fmaf(wg, v.x, acc[s][i].x);
                acc[s][i].y = fmaf(wg, v.y, acc[s][i].y);
                acc[s][i].z = fmaf(wg, v.z, acc[s][i].z);
                acc[s][i].w = fmaf(wg, v.w, acc[s][i].w);
            }
            v = n; kcur = knext; rcur = rnext;
        }
    }

    // Epilogue: per (task s, i) transpose via LDS, store full 64 B lines.
    __shared__ float tile[256][17];
#pragma unroll
    for (int s = 0; s < 2; ++s) {
        const int band = s ? 3 - j : j;
        const int Bq   = s ? 7 - Bp : Bp;
        const int col  = 4 * p + band;     // f2 - 16q
#pragma unroll
        for (int i = 0; i < 4; ++i) {
            __syncthreads();               // protect tile reuse
            if (lane < Lq) {
                const int rb = 4 * lane;
#pragma unroll
                for (int r = 0; r < 4; ++r)
                    tile[rb + r][col] = (&acc[s][i].x)[r];
            }
            __syncthreads();
            const int b2  = 4 * Bq + i;
            const int row = tid >> 2;
            const int c4  = tid & 3;
            if (row < Lt) {
                float4 v4 = make_float4(tile[row][4 * c4 + 0], tile[row][4 * c4 + 1],
                                        tile[row][4 * c4 + 2], tile[row][4 * c4 + 3]);
                *reinterpret_cast<float4*>(
                    out + ((size_t)b2 * T_LEN + t0 + row) * NF + 16 * q + 4 * c4) = v4;
            }
        }
    }
}

extern "C" void kernel_launch(void* const* d_in, const int* in_sizes, int n_in,
                              void* d_out, int out_size, void* d_ws, size_t ws_size,
                              hipStream_t stream) {
    const float* spec = (const float*)d_in[0];   // (32, 1025, 2000) f32
    const float* cf   = (const float*)d_in[1];   // (128,)
    const float* bwv  = (const float*)d_in[2];   // (128,)
    const float* fs   = (const float*)d_in[3];   // (128, 2)
    float* out = (float*)d_out;                  // (32, 2000, 128) f32

    fb_fused<<<dim3(8, 4, 8), 1024, 0, stream>>>(spec, cf, bwv, fs, out);
}